// Round 8
// baseline (4825.731 us; speedup 1.0000x reference)
//
#include <hip/hip_runtime.h>
#include <stdint.h>

constexpr int kN    = 100000;   // nodes
constexpr int kDOut = 128;      // output dim
constexpr int kDIn  = 256;      // input feature dim
constexpr int kNNZ  = 3200000;  // nnz for both X and A
constexpr float kInvKeep = (float)(1.0 / 0.9);

constexpr int kRPB = 32;                 // rows per bucket
constexpr int kNB  = kN / kRPB;          // 3125 buckets (exact)
constexpr int kPad = 16;                 // counter padding: 16 ints = 64B line

// ---------------- RNG (verified round 4: partitionable, bits = o0^o1) -----
__device__ __forceinline__ uint32_t rotl32(uint32_t v, int r) {
  return (v << r) | (v >> (32 - r));
}
__device__ __forceinline__ void threefry2x32(uint32_t k0, uint32_t k1,
                                             uint32_t x0, uint32_t x1,
                                             uint32_t& o0, uint32_t& o1) {
  const uint32_t ks0 = k0, ks1 = k1, ks2 = k0 ^ k1 ^ 0x1BD11BDAu;
  x0 += ks0; x1 += ks1;
#define TF_RND(r) { x0 += x1; x1 = rotl32(x1, (r)); x1 ^= x0; }
  TF_RND(13) TF_RND(15) TF_RND(26) TF_RND(6)
  x0 += ks1; x1 += ks2 + 1u;
  TF_RND(17) TF_RND(29) TF_RND(16) TF_RND(24)
  x0 += ks2; x1 += ks0 + 2u;
  TF_RND(13) TF_RND(15) TF_RND(26) TF_RND(6)
  x0 += ks0; x1 += ks1 + 3u;
  TF_RND(17) TF_RND(29) TF_RND(16) TF_RND(24)
  x0 += ks1; x1 += ks2 + 4u;
  TF_RND(13) TF_RND(15) TF_RND(26) TF_RND(6)
  x0 += ks2; x1 += ks0 + 5u;
#undef TF_RND
  o0 = x0; o1 = x1;
}
__device__ __forceinline__ float keep_mask(uint32_t i) {
  uint32_t o0, o1;
  threefry2x32(0u, 42u, 0u, i, o0, o1);
  uint32_t bits = o0 ^ o1;
  float u = __uint_as_float((bits >> 9) | 0x3f800000u) - 1.0f;
  return floorf(0.9f + u);
}

// ---------------- bf16 helpers (RTNE) --------------------------------------
__device__ __forceinline__ uint32_t f32_to_bf16(float f) {
  uint32_t u = __float_as_uint(f);
  u += 0x7fffu + ((u >> 16) & 1u);
  return u >> 16;
}
__device__ __forceinline__ float bf16lo_to_f32(uint32_t packed) {
  return __uint_as_float(packed << 16);
}
__device__ __forceinline__ float bf16hi_to_f32(uint32_t packed) {
  return __uint_as_float(packed & 0xffff0000u);
}

// ---------------- bucket histogram ------------------------------------------
template<bool DROPOUT>
__global__ void bhist_kernel(const int* __restrict__ rows, int* __restrict__ bcnt,
                             int nnz) {
  int e = blockIdx.x * blockDim.x + threadIdx.x;
  if (e >= nnz) return;
  if (DROPOUT && keep_mask((uint32_t)e) == 0.0f) return;
  int b = rows[e] >> 5;   // kRPB = 32
  atomicAdd(&bcnt[b * kPad], 1);
}

// ---------------- bucket scan (single block, 256 thr x 16 = 4096 >= 3125) --
__global__ void bscan_kernel(const int* __restrict__ bcnt, int* __restrict__ bptr,
                             int* __restrict__ bcur) {
  __shared__ int sd[256];
  int t = threadIdx.x;
  int v[16]; int s = 0;
  #pragma unroll
  for (int k = 0; k < 16; ++k) {
    int idx = t * 16 + k;
    v[k] = (idx < kNB) ? bcnt[idx * kPad] : 0;
    s += v[k];
  }
  sd[t] = s; __syncthreads();
  #pragma unroll
  for (int off = 1; off < 256; off <<= 1) {
    int x = (t >= off) ? sd[t - off] : 0;
    __syncthreads();
    sd[t] += x;
    __syncthreads();
  }
  int run = (t == 0) ? 0 : sd[t - 1];
  #pragma unroll
  for (int k = 0; k < 16; ++k) {
    int idx = t * 16 + k;
    if (idx < kNB) { bptr[idx] = run; bcur[idx * kPad] = run; }
    run += v[k];
  }
  if (t == 255) bptr[kNB] = sd[255];
}

// ---------------- bucket scatter: (rl<<24 | col, val) 8B per edge ----------
template<bool DROPOUT>
__global__ void bscatter_kernel(const int* __restrict__ rows,
                                const int* __restrict__ cols,
                                const float* __restrict__ vals,
                                int* __restrict__ bcur,
                                uint64_t* __restrict__ spack, int nnz) {
  int e = blockIdx.x * blockDim.x + threadIdx.x;
  if (e >= nnz) return;
  float v = vals[e];
  if (DROPOUT) {
    if (keep_mask((uint32_t)e) == 0.0f) return;
    v *= kInvKeep;
  }
  int r = rows[e];
  int b = r >> 5;
  uint32_t rl = (uint32_t)(r & 31);
  int pos = atomicAdd(&bcur[b * kPad], 1);
  uint32_t lo = (uint32_t)cols[e] | (rl << 24);
  spack[pos] = (uint64_t)lo | ((uint64_t)__float_as_uint(v) << 32);
}

// ---------------- W (f32, [kDIn][kDOut]) -> bf16 copy ----------------------
__global__ void wcvt_kernel(const float* __restrict__ W, uint16_t* __restrict__ Wb) {
  int i = blockIdx.x * blockDim.x + threadIdx.x;
  if (i < kDIn * kDOut) Wb[i] = (uint16_t)f32_to_bf16(W[i]);
}

// ---------------- bucketed SpMM with LDS accumulation ----------------------
// One block per bucket. acc[32 rows][128 dims] f32 in LDS (16 KB).
// Each wave processes 4 edges per unrolled iter: all 64 lanes share the edge
// (uniform 8B load), lane covers dims 2*lane, 2*lane+1 via one bf16x2 gather.
template<bool OUT_BF16, bool RELU>
__global__ void bspmm_kernel(const int* __restrict__ bptr,
                             const uint64_t* __restrict__ spack,
                             const uint16_t* __restrict__ B,   // bf16 [*, kDOut]
                             void* __restrict__ outv) {
  __shared__ float acc[kRPB * kDOut];   // 4096 f32 = 16 KB
  const int tid = threadIdx.x;
  const int b = blockIdx.x;
  #pragma unroll
  for (int i = tid; i < kRPB * kDOut; i += 256) acc[i] = 0.0f;
  __syncthreads();

  const int s = bptr[b], e = bptr[b + 1];
  const int w = tid >> 6, lane = tid & 63;
  const int dof = 2 * lane;

  for (int base = s + w * 4; base < e; base += 16) {
    uint64_t p[4];
    #pragma unroll
    for (int k = 0; k < 4; ++k)
      p[k] = (base + k < e) ? spack[base + k] : 0ull;   // v=+0 -> harmless
    uint32_t g[4];
    #pragma unroll
    for (int k = 0; k < 4; ++k) {
      uint32_t c = (uint32_t)p[k] & 0x00ffffffu;
      g[k] = *(const uint32_t*)(B + (size_t)c * kDOut + dof);
    }
    #pragma unroll
    for (int k = 0; k < 4; ++k) {
      float v = __uint_as_float((uint32_t)(p[k] >> 32));
      int rl = (int)(((uint32_t)p[k]) >> 24);
      atomicAdd(&acc[rl * kDOut + dof],     v * bf16lo_to_f32(g[k]));
      atomicAdd(&acc[rl * kDOut + dof + 1], v * bf16hi_to_f32(g[k]));
    }
  }
  __syncthreads();

  const int rowbase = b * kRPB;
  #pragma unroll
  for (int i2 = tid; i2 < kRPB * (kDOut / 2); i2 += 256) {
    int rl = i2 >> 6;          // kDOut/2 = 64 pairs per row
    int d2 = i2 & 63;
    float a0 = acc[rl * kDOut + 2 * d2];
    float a1 = acc[rl * kDOut + 2 * d2 + 1];
    if (RELU) { a0 = fmaxf(a0, 0.0f); a1 = fmaxf(a1, 0.0f); }
    if (OUT_BF16) {
      uint32_t pk = f32_to_bf16(a0) | (f32_to_bf16(a1) << 16);
      ((uint32_t*)outv)[(size_t)(rowbase + rl) * 64 + d2] = pk;
    } else {
      float2 f; f.x = a0; f.y = a1;
      ((float2*)outv)[(size_t)(rowbase + rl) * 64 + d2] = f;
    }
  }
}

// ---------------------------------------------------------------------------
extern "C" void kernel_launch(void* const* d_in, const int* in_sizes, int n_in,
                              void* d_out, int out_size, void* d_ws, size_t ws_size,
                              hipStream_t stream) {
  const int*   x_rows   = (const int*)d_in[0];
  const int*   x_cols   = (const int*)d_in[1];
  const float* x_vals   = (const float*)d_in[2];
  const int*   adj_rows = (const int*)d_in[3];
  const int*   adj_cols = (const int*)d_in[4];
  const float* adj_vals = (const float*)d_in[5];
  const float* W        = (const float*)d_in[6];
  float* out = (float*)d_out;

  // workspace layout (256B-aligned chunks)
  size_t off = 0;
  auto take = [&](size_t bytes) -> char* {
    char* p = (char*)d_ws + off;
    off += (bytes + 255) & ~(size_t)255;
    return p;
  };
  uint16_t* hb    = (uint16_t*)take((size_t)kN * kDOut * 2);    // 25.6 MB
  uint16_t* Wb    = (uint16_t*)take((size_t)kDIn * kDOut * 2);  // 64 KB
  int*      bptr  = (int*)take((size_t)(kNB + 1) * 4);          // 12.5 KB
  int*      bcnt  = (int*)take((size_t)kNB * kPad * 4);         // 200 KB (64B-padded)
  int*      bcur  = (int*)take((size_t)kNB * kPad * 4);         // 200 KB
  uint64_t* spack = (uint64_t*)take((size_t)kNNZ * 8);          // 25.6 MB
  const size_t needed = off;                                    // ~51.7 MB
  if (ws_size < needed) return;  // round-5 proved ws >= 77.7 MB

  const int edgeBlocks = (kNNZ + 255) / 256;

  wcvt_kernel<<<(kDIn * kDOut + 255) / 256, 256, 0, stream>>>(W, Wb);

  // ---------- X: bucket build (dropout folded) + bspmm1 -> hb ----------
  hipMemsetAsync(bcnt, 0, (size_t)kNB * kPad * 4, stream);
  bhist_kernel<true><<<edgeBlocks, 256, 0, stream>>>(x_rows, bcnt, kNNZ);
  bscan_kernel<<<1, 256, 0, stream>>>(bcnt, bptr, bcur);
  bscatter_kernel<true><<<edgeBlocks, 256, 0, stream>>>(
      x_rows, x_cols, x_vals, bcur, spack, kNNZ);
  bspmm_kernel<true, false><<<kNB, 256, 0, stream>>>(bptr, spack, Wb, hb);

  // ---------- adj: bucket build + bspmm2(+relu) -> out ----------
  hipMemsetAsync(bcnt, 0, (size_t)kNB * kPad * 4, stream);
  bhist_kernel<false><<<edgeBlocks, 256, 0, stream>>>(adj_rows, bcnt, kNNZ);
  bscan_kernel<<<1, 256, 0, stream>>>(bcnt, bptr, bcur);
  bscatter_kernel<false><<<edgeBlocks, 256, 0, stream>>>(
      adj_rows, adj_cols, adj_vals, bcur, spack, kNNZ);
  bspmm_kernel<false, true><<<kNB, 256, 0, stream>>>(bptr, spack, hb, out);
}

// Round 9
// 928.865 us; speedup vs baseline: 5.1953x; 5.1953x over previous
//
#include <hip/hip_runtime.h>
#include <stdint.h>

constexpr int kN    = 100000;   // nodes
constexpr int kDOut = 128;      // output dim
constexpr int kDIn  = 256;      // input feature dim
constexpr int kNNZ  = 3200000;  // nnz for both X and A
constexpr float kInvKeep = (float)(1.0 / 0.9);

constexpr int kSlabs   = 4;               // scatter destination tiles
constexpr int kSlabLen = kN / kSlabs;     // 25000 rows per slab (exact)

// ---------------- RNG (verified round 4: partitionable, bits = o0^o1) -----
__device__ __forceinline__ uint32_t rotl32(uint32_t v, int r) {
  return (v << r) | (v >> (32 - r));
}
__device__ __forceinline__ void threefry2x32(uint32_t k0, uint32_t k1,
                                             uint32_t x0, uint32_t x1,
                                             uint32_t& o0, uint32_t& o1) {
  const uint32_t ks0 = k0, ks1 = k1, ks2 = k0 ^ k1 ^ 0x1BD11BDAu;
  x0 += ks0; x1 += ks1;
#define TF_RND(r) { x0 += x1; x1 = rotl32(x1, (r)); x1 ^= x0; }
  TF_RND(13) TF_RND(15) TF_RND(26) TF_RND(6)
  x0 += ks1; x1 += ks2 + 1u;
  TF_RND(17) TF_RND(29) TF_RND(16) TF_RND(24)
  x0 += ks2; x1 += ks0 + 2u;
  TF_RND(13) TF_RND(15) TF_RND(26) TF_RND(6)
  x0 += ks0; x1 += ks1 + 3u;
  TF_RND(17) TF_RND(29) TF_RND(16) TF_RND(24)
  x0 += ks1; x1 += ks2 + 4u;
  TF_RND(13) TF_RND(15) TF_RND(26) TF_RND(6)
  x0 += ks2; x1 += ks0 + 5u;
#undef TF_RND
  o0 = x0; o1 = x1;
}
__device__ __forceinline__ float keep_mask(uint32_t i) {
  uint32_t o0, o1;
  threefry2x32(0u, 42u, 0u, i, o0, o1);
  uint32_t bits = o0 ^ o1;
  float u = __uint_as_float((bits >> 9) | 0x3f800000u) - 1.0f;
  return floorf(0.9f + u);
}

// ---------------- bf16 helpers (RTNE) --------------------------------------
__device__ __forceinline__ uint16_t f32_to_bf16(float f) {
  uint32_t u = __float_as_uint(f);
  u += 0x7fffu + ((u >> 16) & 1u);
  return (uint16_t)(u >> 16);
}
__device__ __forceinline__ float bf16lo_to_f32(uint32_t packed) {
  return __uint_as_float(packed << 16);
}
__device__ __forceinline__ float bf16hi_to_f32(uint32_t packed) {
  return __uint_as_float(packed & 0xffff0000u);
}

// ---------------- CSR build: histogram -> scan -> tiled scatter ------------
template<bool DROPOUT>
__global__ void hist_kernel(const int* __restrict__ rows, int* __restrict__ cnt,
                            int nnz) {
  int e = blockIdx.x * blockDim.x + threadIdx.x;
  if (e >= nnz) return;
  if (DROPOUT && keep_mask((uint32_t)e) == 0.0f) return;
  atomicAdd(&cnt[rows[e]], 1);
}

constexpr int kScanChunk = 2048;   // 256 threads x 8 elems
constexpr int kScanBlk   = (kN + kScanChunk - 1) / kScanChunk;  // 49

__global__ void scan1_kernel(const int* __restrict__ cnt, int* __restrict__ rowptr,
                             int* __restrict__ partials, int n) {
  __shared__ int sd[256];
  int b = blockIdx.x, t = threadIdx.x;
  int base = b * kScanChunk + t * 8;
  int v[8]; int s = 0;
  #pragma unroll
  for (int k = 0; k < 8; ++k) { int idx = base + k; v[k] = (idx < n) ? cnt[idx] : 0; s += v[k]; }
  sd[t] = s; __syncthreads();
  #pragma unroll
  for (int off = 1; off < 256; off <<= 1) {
    int x = (t >= off) ? sd[t - off] : 0;
    __syncthreads();
    sd[t] += x;
    __syncthreads();
  }
  if (t == 255) partials[b] = sd[255];
  int run = (t == 0) ? 0 : sd[t - 1];
  #pragma unroll
  for (int k = 0; k < 8; ++k) { int idx = base + k; if (idx < n) rowptr[idx] = run; run += v[k]; }
}

__global__ void scan2_kernel(int* __restrict__ partials, int* __restrict__ rowptr,
                             int nblk, int n) {
  __shared__ int sd[64];
  int t = threadIdx.x;
  sd[t] = (t < nblk) ? partials[t] : 0;
  __syncthreads();
  #pragma unroll
  for (int off = 1; off < 64; off <<= 1) {
    int x = (t >= off) ? sd[t - off] : 0;
    __syncthreads();
    sd[t] += x;
    __syncthreads();
  }
  if (t < nblk) partials[t] = (t == 0) ? 0 : sd[t - 1];
  if (t == 63) rowptr[n] = sd[63];
}

// finalize rowptr AND seed cur = rowptr (scatter bumps cur directly)
__global__ void scan3_kernel(int* __restrict__ rowptr, int* __restrict__ cur,
                             const int* __restrict__ partials, int n) {
  int i = blockIdx.x * blockDim.x + threadIdx.x;
  if (i < n) {
    int v = rowptr[i] + partials[i / kScanChunk];
    rowptr[i] = v;
    cur[i] = v;
  }
}

// one destination slab per pass: rows in [lo, hi) only. Writes land in a
// contiguous ~6.4MB spack window -> L2 lines fill before eviction.
template<bool DROPOUT>
__global__ void scatter_kernel(const int* __restrict__ rows,
                               const int* __restrict__ cols,
                               const float* __restrict__ vals,
                               int* __restrict__ cur,
                               uint2* __restrict__ spack, int nnz,
                               int lo, int hi) {
  int e = blockIdx.x * blockDim.x + threadIdx.x;
  if (e >= nnz) return;
  int r = rows[e];
  if (r < lo || r >= hi) return;
  if (DROPOUT && keep_mask((uint32_t)e) == 0.0f) return;
  float v = vals[e];
  if (DROPOUT) v *= kInvKeep;
  int pos = atomicAdd(&cur[r], 1);
  uint2 p;
  p.x = (uint32_t)cols[e];
  p.y = __float_as_uint(v);
  spack[pos] = p;
}

// ---------------- W (f32, [kDIn][kDOut]) -> bf16 copy ----------------------
__global__ void wcvt_kernel(const float* __restrict__ W, uint16_t* __restrict__ Wb) {
  int i = blockIdx.x * blockDim.x + threadIdx.x;
  if (i < kDIn * kDOut) Wb[i] = f32_to_bf16(W[i]);
}

// ---------------- CSR SpMM, bf16 B-matrix (round-6 validated) --------------
// 4 rows per 256-thread block; 64 lanes/row; lane computes d=2*lane, 2*lane+1
// via one 4B bf16x2 gather per edge.
template<bool OUT_BF16, bool RELU>
__global__ void spmm_csr_kernel(const int* __restrict__ rowptr,
                                const uint2* __restrict__ spack,
                                const uint16_t* __restrict__ B,  // bf16 [*, kDOut]
                                void* __restrict__ outv, int nrows) {
  int tid = threadIdx.x;
  int row = blockIdx.x * 4 + (tid >> 6);
  int lane = tid & 63;
  if (row >= nrows) return;
  int e = rowptr[row], e_end = rowptr[row + 1];
  float a0 = 0.0f, a1 = 0.0f;
  const int doff = lane * 2;
  for (; e + 1 < e_end; e += 2) {
    uint2 p0 = spack[e], p1 = spack[e + 1];
    float v0 = __uint_as_float(p0.y);
    float v1 = __uint_as_float(p1.y);
    uint32_t g0 = *(const uint32_t*)(B + (size_t)p0.x * kDOut + doff);
    uint32_t g1 = *(const uint32_t*)(B + (size_t)p1.x * kDOut + doff);
    a0 += v0 * bf16lo_to_f32(g0);
    a1 += v0 * bf16hi_to_f32(g0);
    a0 += v1 * bf16lo_to_f32(g1);
    a1 += v1 * bf16hi_to_f32(g1);
  }
  if (e < e_end) {
    uint2 p0 = spack[e];
    float v0 = __uint_as_float(p0.y);
    uint32_t g0 = *(const uint32_t*)(B + (size_t)p0.x * kDOut + doff);
    a0 += v0 * bf16lo_to_f32(g0);
    a1 += v0 * bf16hi_to_f32(g0);
  }
  if (RELU) { a0 = fmaxf(a0, 0.0f); a1 = fmaxf(a1, 0.0f); }
  if (OUT_BF16) {
    uint32_t packed = (uint32_t)f32_to_bf16(a0) | ((uint32_t)f32_to_bf16(a1) << 16);
    ((uint32_t*)outv)[(size_t)row * (kDOut / 2) + lane] = packed;
  } else {
    float2 o; o.x = a0; o.y = a1;
    ((float2*)outv)[(size_t)row * (kDOut / 2) + lane] = o;
  }
}

// ---------------------------------------------------------------------------
extern "C" void kernel_launch(void* const* d_in, const int* in_sizes, int n_in,
                              void* d_out, int out_size, void* d_ws, size_t ws_size,
                              hipStream_t stream) {
  const int*   x_rows   = (const int*)d_in[0];
  const int*   x_cols   = (const int*)d_in[1];
  const float* x_vals   = (const float*)d_in[2];
  const int*   adj_rows = (const int*)d_in[3];
  const int*   adj_cols = (const int*)d_in[4];
  const float* adj_vals = (const float*)d_in[5];
  const float* W        = (const float*)d_in[6];
  float* out = (float*)d_out;

  // workspace layout (256B-aligned chunks)
  size_t off = 0;
  auto take = [&](size_t bytes) -> char* {
    char* p = (char*)d_ws + off;
    off += (bytes + 255) & ~(size_t)255;
    return p;
  };
  uint16_t* hb     = (uint16_t*)take((size_t)kN * kDOut * 2);   // 25.6 MB (bf16 h)
  uint16_t* Wb     = (uint16_t*)take((size_t)kDIn * kDOut * 2); // 64 KB
  int*      rowptr = (int*)take((size_t)(kN + 1) * 4);          // 400 KB
  int*      cur    = (int*)take((size_t)kN * 4);                // 400 KB
  uint2*    spack  = (uint2*)take((size_t)kNNZ * 8);            // 25.6 MB
  int*      partials = (int*)take(64 * 4);
  const size_t needed = off;                                    // ~52.3 MB
  if (ws_size < needed) return;

  const int edgeBlocks = (kNNZ + 255) / 256;
  const int spmmBlocks = (kN + 3) / 4;

  wcvt_kernel<<<(kDIn * kDOut + 255) / 256, 256, 0, stream>>>(W, Wb);

  // ---------- X: CSR build (dropout folded) + spmm1 -> hb ----------
  hipMemsetAsync(cur, 0, (size_t)kN * 4, stream);
  hist_kernel<true><<<edgeBlocks, 256, 0, stream>>>(x_rows, cur, kNNZ);
  scan1_kernel<<<kScanBlk, 256, 0, stream>>>(cur, rowptr, partials, kN);
  scan2_kernel<<<1, 64, 0, stream>>>(partials, rowptr, kScanBlk, kN);
  scan3_kernel<<<(kN + 255) / 256, 256, 0, stream>>>(rowptr, cur, partials, kN);
  for (int p = 0; p < kSlabs; ++p) {
    scatter_kernel<true><<<edgeBlocks, 256, 0, stream>>>(
        x_rows, x_cols, x_vals, cur, spack, kNNZ,
        p * kSlabLen, (p + 1) * kSlabLen);
  }
  spmm_csr_kernel<true, false><<<spmmBlocks, 256, 0, stream>>>(
      rowptr, spack, Wb, hb, kN);

  // ---------- adj: CSR build (reuse buffers) + spmm2(+relu) -> out ----------
  hipMemsetAsync(cur, 0, (size_t)kN * 4, stream);
  hist_kernel<false><<<edgeBlocks, 256, 0, stream>>>(adj_rows, cur, kNNZ);
  scan1_kernel<<<kScanBlk, 256, 0, stream>>>(cur, rowptr, partials, kN);
  scan2_kernel<<<1, 64, 0, stream>>>(partials, rowptr, kScanBlk, kN);
  scan3_kernel<<<(kN + 255) / 256, 256, 0, stream>>>(rowptr, cur, partials, kN);
  for (int p = 0; p < kSlabs; ++p) {
    scatter_kernel<false><<<edgeBlocks, 256, 0, stream>>>(
        adj_rows, adj_cols, adj_vals, cur, spack, kNNZ,
        p * kSlabLen, (p + 1) * kSlabLen);
  }
  spmm_csr_kernel<false, true><<<spmmBlocks, 256, 0, stream>>>(
      rowptr, spack, hb, out, kN);
}